// Round 6
// baseline (378.060 us; speedup 1.0000x reference)
//
#include <hip/hip_runtime.h>
#include <hip/hip_bf16.h>

// Problem constants (B=1)
#define SEQ   2048
#define HID   2048
#define NH    16
#define NKV   2
#define DH    128
#define QKVN  2560                       // 2048 (Q) + 256 (K) + 256 (V)
#define SCALE 0.08838834764831845f      // 1/sqrt(128)
#define LOG2E 1.4426950408889634f

typedef short bf16x8 __attribute__((ext_vector_type(8)));
typedef short bf16x4 __attribute__((ext_vector_type(4)));
typedef float f32x4  __attribute__((ext_vector_type(4)));

__device__ __forceinline__ short f2bf(float x) {
    unsigned u = __float_as_uint(x);
    u += 0x7FFF + ((u >> 16) & 1);          // round-to-nearest-even
    return (short)(u >> 16);
}

__device__ __forceinline__ void gl2lds16(const short* g, short* l) {
    __builtin_amdgcn_global_load_lds(
        (const __attribute__((address_space(1))) int*)g,
        (__attribute__((address_space(3))) int*)l, 16, 0, 0);
}

// ---------------------------------------------------------------------------
// fp32 -> bf16 elementwise (4 elems/thread)
// ---------------------------------------------------------------------------
__global__ void cvt_bf16(const float* __restrict__ s, short* __restrict__ d)
{
    int i = blockIdx.x * 256 + threadIdx.x;
    float4 v = ((const float4*)s)[i];
    bf16x4 o = { f2bf(v.x), f2bf(v.y), f2bf(v.z), f2bf(v.w) };
    ((bf16x4*)d)[i] = o;
}

// ---------------------------------------------------------------------------
// fp32 [K][N] -> bf16 [N][K] transpose+convert. Block (32,8), tile 32x32.
// ---------------------------------------------------------------------------
__global__ void transp_bf(const float* __restrict__ src, short* __restrict__ dst,
                          int N, int K)
{
    __shared__ short t[32][33];
    int bx = blockIdx.x * 32;      // n tile
    int by = blockIdx.y * 32;      // k tile
    int lx = threadIdx.x, ly = threadIdx.y;
#pragma unroll
    for (int i = 0; i < 4; ++i)
        t[ly + i * 8][lx] = f2bf(src[(size_t)(by + ly + i * 8) * N + bx + lx]);
    __syncthreads();
#pragma unroll
    for (int i = 0; i < 4; ++i)
        dst[(size_t)(bx + ly + i * 8) * K + by + lx] = t[lx][ly + i * 8];
}

// ---------------------------------------------------------------------------
// bf16 MFMA GEMM (m97 structure): C[M,N] = A[M,K] @ Bt[N,K]^T (+bias).
// ---------------------------------------------------------------------------
__global__ __launch_bounds__(256) void gemm_bt(const short* __restrict__ A,
                                               const short* __restrict__ Bt,
                                               const float* __restrict__ bias,
                                               float* __restrict__ C,
                                               int M, int N, int K)
{
    __shared__ short As[128 * 32];     // row-major [128][32], no padding
    __shared__ short Bs[128 * 32];

    const int tid  = threadIdx.x;
    const int wave = tid >> 6;
    const int lane = tid & 63;
    const int quad = lane >> 4;
    const int l16  = lane & 15;
    const int m0 = blockIdx.y * 128;
    const int n0 = blockIdx.x * 128;
    const int wm = (wave >> 1) * 64;
    const int wn = (wave & 1) * 64;

    const int r0 = tid >> 2;
    const int c0 = (tid & 3) * 8;
    const short* gA = A  + (size_t)(m0 + r0) * K + c0;
    const short* gB = Bt + (size_t)(n0 + r0) * K + c0;
    short* lA = As + wave * 512;
    short* lB = Bs + wave * 512;

    f32x4 acc[4][4];
#pragma unroll
    for (int i = 0; i < 4; ++i)
#pragma unroll
        for (int j = 0; j < 4; ++j) acc[i][j] = (f32x4){0.f, 0.f, 0.f, 0.f};

    for (int k0 = 0; k0 < K; k0 += 32) {
        __syncthreads();
        gl2lds16(gA + k0,                  lA);
        gl2lds16(gA + k0 + (size_t)64 * K, lA + 2048);
        gl2lds16(gB + k0,                  lB);
        gl2lds16(gB + k0 + (size_t)64 * K, lB + 2048);
        __syncthreads();

        bf16x8 av[4], bv[4];
#pragma unroll
        for (int mt = 0; mt < 4; ++mt)
            av[mt] = *(const bf16x8*)&As[(wm + mt * 16 + l16) * 32 + quad * 8];
#pragma unroll
        for (int nt = 0; nt < 4; ++nt)
            bv[nt] = *(const bf16x8*)&Bs[(wn + nt * 16 + l16) * 32 + quad * 8];
#pragma unroll
        for (int mt = 0; mt < 4; ++mt)
#pragma unroll
            for (int nt = 0; nt < 4; ++nt)
                acc[mt][nt] = __builtin_amdgcn_mfma_f32_16x16x32_bf16(
                    av[mt], bv[nt], acc[mt][nt], 0, 0, 0);
    }

#pragma unroll
    for (int mt = 0; mt < 4; ++mt)
#pragma unroll
        for (int nt = 0; nt < 4; ++nt) {
            int col = n0 + wn + nt * 16 + l16;
            float b = bias ? bias[col] : 0.f;
#pragma unroll
            for (int r = 0; r < 4; ++r) {
                int row = m0 + wm + mt * 16 + quad * 4 + r;
                C[(size_t)row * N + col] = acc[mt][nt][r] + b;
            }
        }
}

// ---------------------------------------------------------------------------
// RoPE in-place on fp32 Q columns of qkv (row stride QKVN).
// ---------------------------------------------------------------------------
__global__ void rope_kernel(float* __restrict__ x,
                            const float* __restrict__ cosp,
                            const float* __restrict__ sinp)
{
    int idx = blockIdx.x * blockDim.x + threadIdx.x;   // SEQ*NH*64
    int d = idx & 63;
    int h = (idx >> 6) & (NH - 1);
    int s = idx >> 10;
    if (s >= SEQ) return;
    float* base = x + (size_t)s * QKVN + h * DH;
    float x0 = base[d], x1 = base[d + 64];
    float c0 = cosp[s * DH + d],  c1 = cosp[s * DH + d + 64];
    float s0 = sinp[s * DH + d],  s1 = sinp[s * DH + d + 64];
    base[d]      = x0 * c0 - x1 * s0;
    base[d + 64] = x1 * c1 + x0 * s1;
}

// ---------------------------------------------------------------------------
// RoPE K (fp32, row stride QKVN) -> bf16 row-major [s][kvh*128+d].
// ---------------------------------------------------------------------------
__global__ void ropebf_k(const float* __restrict__ kp,
                         const float* __restrict__ cosp,
                         const float* __restrict__ sinp,
                         short* __restrict__ kb)
{
    int idx = blockIdx.x * blockDim.x + threadIdx.x;   // SEQ*NKV*64
    int d   = idx & 63;
    int kvh = (idx >> 6) & (NKV - 1);
    int s   = idx >> 7;
    if (s >= SEQ) return;
    const float* base = kp + (size_t)s * QKVN + kvh * DH;
    float x0 = base[d], x1 = base[d + 64];
    float c0 = cosp[s * DH + d],  c1 = cosp[s * DH + d + 64];
    float s0 = sinp[s * DH + d],  s1 = sinp[s * DH + d + 64];
    short* ob = kb + (size_t)s * (NKV * DH) + kvh * DH;
    ob[d]      = f2bf(x0 * c0 - x1 * s0);
    ob[d + 64] = f2bf(x1 * c1 + x0 * s1);
}

// ---------------------------------------------------------------------------
// V (fp32, row stride QKVN) -> bf16 transposed vt[kvh][d][s]
// ---------------------------------------------------------------------------
__global__ void vt_conv(const float* __restrict__ vp, short* __restrict__ vt)
{
    int idx = blockIdx.x * blockDim.x + threadIdx.x;   // NKV*128*SEQ
    int s   = idx & (SEQ - 1);
    int d   = (idx >> 11) & (DH - 1);
    int kvh = idx >> 18;
    vt[idx] = f2bf(vp[(size_t)s * QKVN + kvh * DH + d]);
}

// ---------------------------------------------------------------------------
// MFMA flash attention v3: transposed scores, 64-key tiles, register
// prefetch of next K/V tile, SL folded into Q, ballot-guarded rescale.
// S^T = mfma(K,Q), O^T = mfma(V^T,P). 2 barriers / 64 keys.
// ---------------------------------------------------------------------------
__global__ __launch_bounds__(256) void attn_mfma(const float* __restrict__ Qp,
                                                 const short* __restrict__ Kb,
                                                 const short* __restrict__ Vtb,
                                                 short* __restrict__ ctx)
{
    __shared__ short Ks[64][136];      // 17.0 KB
    __shared__ short Vs[128][72];      // 18.0 KB
    __shared__ short Ps[4][16][72];    //  9.0 KB  per-wave [q][k]

    const int bid = blockIdx.x;
    const int h   = bid & 15;
    const int qb  = 31 - (bid >> 4);   // heavy q-blocks dispatch first
    const int kvh = h >> 3;
    const int tid  = threadIdx.x;
    const int wave = tid >> 6;
    const int lane = tid & 63;
    const int quad = lane >> 4;
    const int l16  = lane & 15;

    const int qrow0 = qb * 64 + wave * 16;
    const int qg    = qrow0 + l16;       // this lane's q column

    // Q fragment, B-operand layout, pre-scaled by SCALE*LOG2E
    const float SL = SCALE * LOG2E;
    bf16x8 aq[4];
    {
        const float* qsrc = Qp + (size_t)(qrow0 + l16) * QKVN + h * DH + quad * 8;
#pragma unroll
        for (int c = 0; c < 4; ++c) {
            float4 f0 = *(const float4*)(qsrc + c * 32);
            float4 f1 = *(const float4*)(qsrc + c * 32 + 4);
            bf16x8 a;
            a[0] = f2bf(f0.x * SL); a[1] = f2bf(f0.y * SL);
            a[2] = f2bf(f0.z * SL); a[3] = f2bf(f0.w * SL);
            a[4] = f2bf(f1.x * SL); a[5] = f2bf(f1.y * SL);
            a[6] = f2bf(f1.z * SL); a[7] = f2bf(f1.w * SL);
            aq[c] = a;
        }
    }

    f32x4 of[8];
#pragma unroll
    for (int t = 0; t < 8; ++t) of[t] = (f32x4){0.f, 0.f, 0.f, 0.f};
    float m_old = -1e30f, l_sum = 0.f;

    const int nkt = qb + 1;            // 64-key tiles

    // ---- prefetch tile 0 into regs ----
    int4 kreg[4], vreg[4];
#pragma unroll
    for (int i = 0; i < 4; ++i) {
        int cid = tid + i * 256;
        kreg[i] = *(const int4*)(Kb + (size_t)(cid >> 4) * (NKV * DH) + kvh * DH + (cid & 15) * 8);
        vreg[i] = *(const int4*)(Vtb + (size_t)kvh * DH * SEQ + (size_t)(cid >> 3) * SEQ + (cid & 7) * 8);
    }

    for (int kt = 0; kt < nkt; ++kt) {
        const int kbase = kt * 64;
        __syncthreads();               // prev iter done reading LDS
#pragma unroll
        for (int i = 0; i < 4; ++i) {
            int cid = tid + i * 256;
            *(int4*)&Ks[cid >> 4][(cid & 15) * 8] = kreg[i];
        }
#pragma unroll
        for (int i = 0; i < 4; ++i) {
            int cid = tid + i * 256;
            *(int4*)&Vs[cid >> 3][(cid & 7) * 8] = vreg[i];
        }
        if (kt + 1 < nkt) {            // issue next-tile loads; overlap compute
            const int nb = kbase + 64;
#pragma unroll
            for (int i = 0; i < 4; ++i) {
                int cid = tid + i * 256;
                kreg[i] = *(const int4*)(Kb + (size_t)(nb + (cid >> 4)) * (NKV * DH) + kvh * DH + (cid & 15) * 8);
                vreg[i] = *(const int4*)(Vtb + (size_t)kvh * DH * SEQ + (size_t)(cid >> 3) * SEQ + nb + (cid & 7) * 8);
            }
        }
        __syncthreads();

        // wave-uniform causal sub-tile count (16-key subtiles with any valid key)
        const int nsub = min(4, ((qrow0 + 15 - kbase) >> 4) + 1);

        // ---- S^T: D[k=sub*16+quad*4+r][q=l16] ----
        f32x4 s[4];
#pragma unroll
        for (int sub = 0; sub < 4; ++sub) s[sub] = (f32x4){0.f, 0.f, 0.f, 0.f};
#pragma unroll
        for (int sub = 0; sub < 4; ++sub) {
            if (sub < nsub) {
#pragma unroll
                for (int c = 0; c < 4; ++c) {
                    bf16x8 ak = *(const bf16x8*)&Ks[sub * 16 + l16][c * 32 + quad * 8];
                    s[sub] = __builtin_amdgcn_mfma_f32_16x16x32_bf16(ak, aq[c], s[sub], 0, 0, 0);
                }
            }
        }

        // ---- per-lane-column online softmax (log2 domain, SL pre-applied) ----
        float x[16];
#pragma unroll
        for (int sub = 0; sub < 4; ++sub)
#pragma unroll
            for (int r = 0; r < 4; ++r) {
                int kg = kbase + sub * 16 + quad * 4 + r;
                x[sub * 4 + r] = (sub < nsub && kg <= qg) ? s[sub][r] : -1e30f;
            }
        float mr = x[0];
#pragma unroll
        for (int i = 1; i < 16; ++i) mr = fmaxf(mr, x[i]);
        mr = fmaxf(mr, __shfl_xor(mr, 16));
        mr = fmaxf(mr, __shfl_xor(mr, 32));
        float mn    = fmaxf(m_old, mr);
        float alpha = __builtin_amdgcn_exp2f(m_old - mn);
        float p[16], ps = 0.f;
#pragma unroll
        for (int i = 0; i < 16; ++i) { p[i] = __builtin_amdgcn_exp2f(x[i] - mn); ps += p[i]; }
        ps += __shfl_xor(ps, 16);
        ps += __shfl_xor(ps, 32);
        l_sum = l_sum * alpha + ps;

        // P^T -> Ps[wave][q=l16][k] (operand layout), 4x 8B stores
#pragma unroll
        for (int sub = 0; sub < 4; ++sub) {
            bf16x4 wv = { f2bf(p[sub * 4 + 0]), f2bf(p[sub * 4 + 1]),
                          f2bf(p[sub * 4 + 2]), f2bf(p[sub * 4 + 3]) };
            *(bf16x4*)&Ps[wave][l16][sub * 16 + quad * 4] = wv;
        }

        // rescale O^T only when some lane's max moved (wave-uniform branch)
        if (__ballot(mn > m_old)) {
#pragma unroll
            for (int t = 0; t < 8; ++t)
#pragma unroll
                for (int r = 0; r < 4; ++r) of[t][r] *= alpha;
        }
        m_old = mn;

        // ---- O^T += V^T @ P  (wave-private Ps; chunk1 skipped if masked) ----
        bf16x8 bp0 = *(const bf16x8*)&Ps[wave][l16][quad * 8];
#pragma unroll
        for (int t = 0; t < 8; ++t) {
            bf16x8 av = *(const bf16x8*)&Vs[t * 16 + l16][quad * 8];
            of[t] = __builtin_amdgcn_mfma_f32_16x16x32_bf16(av, bp0, of[t], 0, 0, 0);
        }
        if (nsub > 2) {
            bf16x8 bp1 = *(const bf16x8*)&Ps[wave][l16][32 + quad * 8];
#pragma unroll
            for (int t = 0; t < 8; ++t) {
                bf16x8 av = *(const bf16x8*)&Vs[t * 16 + l16][32 + quad * 8];
                of[t] = __builtin_amdgcn_mfma_f32_16x16x32_bf16(av, bp1, of[t], 0, 0, 0);
            }
        }
    }

    // epilogue: O^T col=q (this lane), row d = t*16+quad*4+r; 8x 8B stores
    float inv = 1.f / l_sum;
    short* dst = ctx + (size_t)qg * HID + h * DH + quad * 4;
#pragma unroll
    for (int t = 0; t < 8; ++t) {
        bf16x4 wv = { f2bf(of[t][0] * inv), f2bf(of[t][1] * inv),
                      f2bf(of[t][2] * inv), f2bf(of[t][3] * inv) };
        *(bf16x4*)(dst + t * 16) = wv;
    }
}

// ---------------------------------------------------------------------------
extern "C" void kernel_launch(void* const* d_in, const int* in_sizes, int n_in,
                              void* d_out, int out_size, void* d_ws, size_t ws_size,
                              hipStream_t stream)
{
    const float* hs   = (const float*)d_in[0];
    const float* cosp = (const float*)d_in[1];
    const float* sinp = (const float*)d_in[2];
    const float* Wq = (const float*)d_in[4];
    const float* bq = (const float*)d_in[5];
    const float* Wk = (const float*)d_in[6];
    const float* bk = (const float*)d_in[7];
    const float* Wv = (const float*)d_in[8];
    const float* bv = (const float*)d_in[9];
    const float* Wo = (const float*)d_in[10];
    float* out = (float*)d_out;

    char* w = (char*)d_ws;
    short* hsb    = (short*)w;  w += (size_t)SEQ * HID * 2;
    short* btq    = (short*)w;  w += (size_t)QKVN * HID * 2;
    short* wot    = (short*)w;  w += (size_t)HID * HID * 2;
    float* biaskv = (float*)w;  w += QKVN * 4;
    float* qkv    = (float*)w;  w += (size_t)SEQ * QKVN * 4;
    short* kbf    = (short*)w;  w += (size_t)SEQ * (NKV * DH) * 2;
    short* vtb    = (short*)w;  w += (size_t)NKV * DH * SEQ * 2;
    short* ctxb   = (short*)w;

    cvt_bf16<<<(SEQ * HID) / 1024, 256, 0, stream>>>(hs, hsb);

    transp_bf<<<dim3(HID / 32, HID / 32), dim3(32, 8), 0, stream>>>(Wq, btq, HID, HID);
    transp_bf<<<dim3((NKV * DH) / 32, HID / 32), dim3(32, 8), 0, stream>>>(Wk, btq + (size_t)2048 * HID, NKV * DH, HID);
    transp_bf<<<dim3((NKV * DH) / 32, HID / 32), dim3(32, 8), 0, stream>>>(Wv, btq + (size_t)2304 * HID, NKV * DH, HID);
    transp_bf<<<dim3(HID / 32, HID / 32), dim3(32, 8), 0, stream>>>(Wo, wot, HID, HID);

    hipMemcpyAsync(biaskv,        bq, 2048 * 4, hipMemcpyDeviceToDevice, stream);
    hipMemcpyAsync(biaskv + 2048, bk,  256 * 4, hipMemcpyDeviceToDevice, stream);
    hipMemcpyAsync(biaskv + 2304, bv,  256 * 4, hipMemcpyDeviceToDevice, stream);

    gemm_bt<<<dim3(QKVN / 128, SEQ / 128), 256, 0, stream>>>(hsb, btq, biaskv, qkv, SEQ, QKVN, HID);

    rope_kernel<<<(SEQ * NH * 64) / 256, 256, 0, stream>>>(qkv, cosp, sinp);
    ropebf_k<<<(SEQ * NKV * 64) / 256, 256, 0, stream>>>(qkv + NH * DH, cosp, sinp, kbf);
    vt_conv<<<(NKV * DH * SEQ) / 256, 256, 0, stream>>>(qkv + NH * DH + NKV * DH, vtb);

    attn_mfma<<<dim3(32 * NH), 256, 0, stream>>>(qkv, kbf, vtb, ctxb);

    gemm_bt<<<dim3(HID / 128, SEQ / 128), 256, 0, stream>>>(ctxb, wot, nullptr, out, SEQ, HID, HID);
}

// Round 7
// 331.687 us; speedup vs baseline: 1.1398x; 1.1398x over previous
//
#include <hip/hip_runtime.h>
#include <hip/hip_bf16.h>

// Problem constants (B=1)
#define SEQ   2048
#define HID   2048
#define NH    16
#define NKV   2
#define DH    128
#define QKVN  2560                       // 2048 (Q) + 256 (K) + 256 (V)
#define SCALE 0.08838834764831845f      // 1/sqrt(128)
#define LOG2E 1.4426950408889634f

typedef short bf16x8 __attribute__((ext_vector_type(8)));
typedef short bf16x4 __attribute__((ext_vector_type(4)));
typedef float f32x4  __attribute__((ext_vector_type(4)));

__device__ __forceinline__ short f2bf(float x) {
    unsigned u = __float_as_uint(x);
    u += 0x7FFF + ((u >> 16) & 1);          // round-to-nearest-even
    return (short)(u >> 16);
}

__device__ __forceinline__ void gl2lds16(const short* g, short* l) {
    __builtin_amdgcn_global_load_lds(
        (const __attribute__((address_space(1))) int*)g,
        (__attribute__((address_space(3))) int*)l, 16, 0, 0);
}

// ---------------------------------------------------------------------------
// All four weight transposes in one launch. fp32 [K][N] -> bf16 [N][K].
// Block (32,8), 32x32 tiles. Tile id decodes which weight.
// ---------------------------------------------------------------------------
__global__ void transp_all(const float* __restrict__ Wq,
                           const float* __restrict__ Wk,
                           const float* __restrict__ Wv,
                           const float* __restrict__ Wo,
                           short* __restrict__ btq,   // [2560][2048]
                           short* __restrict__ wot)   // [2048][2048]
{
    __shared__ short t[32][33];
    const int tb = blockIdx.x;
    const float* src; short* dst; int N, bx, by;
    if (tb < 4096)      { src = Wq; dst = btq;                        N = 2048; int u = tb;        bx = (u & 63) * 32; by = (u >> 6) * 32; }
    else if (tb < 4608) { src = Wk; dst = btq + (size_t)2048 * HID;   N = 256;  int u = tb - 4096; bx = (u & 7) * 32;  by = (u >> 3) * 32; }
    else if (tb < 5120) { src = Wv; dst = btq + (size_t)2304 * HID;   N = 256;  int u = tb - 4608; bx = (u & 7) * 32;  by = (u >> 3) * 32; }
    else                { src = Wo; dst = wot;                        N = 2048; int u = tb - 5120; bx = (u & 63) * 32; by = (u >> 6) * 32; }
    const int K = HID;
    int lx = threadIdx.x, ly = threadIdx.y;
#pragma unroll
    for (int i = 0; i < 4; ++i)
        t[ly + i * 8][lx] = f2bf(src[(size_t)(by + ly + i * 8) * N + bx + lx]);
    __syncthreads();
#pragma unroll
    for (int i = 0; i < 4; ++i)
        dst[(size_t)(bx + ly + i * 8) * K + by + lx] = t[lx][ly + i * 8];
}

// ---------------------------------------------------------------------------
// QKV GEMM: C[M,2560] = A_f32[M,K] @ Bt[2560,K]^T + bias(concat q,k,v).
// A staged with in-register f32->bf16 convert; B via global_load_lds.
// ---------------------------------------------------------------------------
__global__ __launch_bounds__(256) void gemm_qkv(const float* __restrict__ A,
                                                const short* __restrict__ Bt,
                                                const float* __restrict__ bq,
                                                const float* __restrict__ bk,
                                                const float* __restrict__ bv,
                                                float* __restrict__ C)
{
    const int K = HID, N = QKVN;
    __shared__ short As[128 * 32];
    __shared__ short Bs[128 * 32];

    const int tid  = threadIdx.x;
    const int wave = tid >> 6;
    const int lane = tid & 63;
    const int quad = lane >> 4;
    const int l16  = lane & 15;
    const int m0 = blockIdx.y * 128;
    const int n0 = blockIdx.x * 128;
    const int wm = (wave >> 1) * 64;
    const int wn = (wave & 1) * 64;

    const int r0 = tid >> 2;
    const int c0 = (tid & 3) * 8;
    const float* gA = A + (size_t)(m0 + r0) * K + c0;
    const short* gB = Bt + (size_t)(n0 + r0) * K + c0;
    short* lB = Bs + wave * 512;

    f32x4 acc[4][4];
#pragma unroll
    for (int i = 0; i < 4; ++i)
#pragma unroll
        for (int j = 0; j < 4; ++j) acc[i][j] = (f32x4){0.f, 0.f, 0.f, 0.f};

    for (int k0 = 0; k0 < K; k0 += 32) {
        __syncthreads();
        // B: async direct-to-LDS
        gl2lds16(gB + k0,                  lB);
        gl2lds16(gB + k0 + (size_t)64 * K, lB + 2048);
        // A: load fp32, convert, store b128
        float4 f0 = *(const float4*)(gA + k0);
        float4 f1 = *(const float4*)(gA + k0 + 4);
        float4 f2 = *(const float4*)(gA + k0 + (size_t)64 * K);
        float4 f3 = *(const float4*)(gA + k0 + (size_t)64 * K + 4);
        bf16x8 a0 = { f2bf(f0.x), f2bf(f0.y), f2bf(f0.z), f2bf(f0.w),
                      f2bf(f1.x), f2bf(f1.y), f2bf(f1.z), f2bf(f1.w) };
        bf16x8 a1 = { f2bf(f2.x), f2bf(f2.y), f2bf(f2.z), f2bf(f2.w),
                      f2bf(f3.x), f2bf(f3.y), f2bf(f3.z), f2bf(f3.w) };
        *(bf16x8*)&As[r0 * 32 + c0]        = a0;
        *(bf16x8*)&As[(r0 + 64) * 32 + c0] = a1;
        __syncthreads();

        bf16x8 av[4], bv4[4];
#pragma unroll
        for (int mt = 0; mt < 4; ++mt)
            av[mt] = *(const bf16x8*)&As[(wm + mt * 16 + l16) * 32 + quad * 8];
#pragma unroll
        for (int nt = 0; nt < 4; ++nt)
            bv4[nt] = *(const bf16x8*)&Bs[(wn + nt * 16 + l16) * 32 + quad * 8];
#pragma unroll
        for (int mt = 0; mt < 4; ++mt)
#pragma unroll
            for (int nt = 0; nt < 4; ++nt)
                acc[mt][nt] = __builtin_amdgcn_mfma_f32_16x16x32_bf16(
                    av[mt], bv4[nt], acc[mt][nt], 0, 0, 0);
    }

#pragma unroll
    for (int nt = 0; nt < 4; ++nt) {
        int col = n0 + wn + nt * 16 + l16;
        // region boundaries (2048, 2304) are multiples of 16: uniform per frag
        float b = (col < 2048) ? bq[col] : (col < 2304 ? bk[col - 2048] : bv[col - 2304]);
#pragma unroll
        for (int mt = 0; mt < 4; ++mt)
#pragma unroll
            for (int r = 0; r < 4; ++r) {
                int row = m0 + wm + mt * 16 + quad * 4 + r;
                C[(size_t)row * N + col] = acc[mt][nt][r] + b;
            }
    }
}

// ---------------------------------------------------------------------------
// bf16 MFMA GEMM (m97 structure): C[M,N] = A[M,K] @ Bt[N,K]^T. (Wo path)
// ---------------------------------------------------------------------------
__global__ __launch_bounds__(256) void gemm_bt(const short* __restrict__ A,
                                               const short* __restrict__ Bt,
                                               float* __restrict__ C,
                                               int M, int N, int K)
{
    __shared__ short As[128 * 32];
    __shared__ short Bs[128 * 32];

    const int tid  = threadIdx.x;
    const int wave = tid >> 6;
    const int lane = tid & 63;
    const int quad = lane >> 4;
    const int l16  = lane & 15;
    const int m0 = blockIdx.y * 128;
    const int n0 = blockIdx.x * 128;
    const int wm = (wave >> 1) * 64;
    const int wn = (wave & 1) * 64;

    const int r0 = tid >> 2;
    const int c0 = (tid & 3) * 8;
    const short* gA = A  + (size_t)(m0 + r0) * K + c0;
    const short* gB = Bt + (size_t)(n0 + r0) * K + c0;
    short* lA = As + wave * 512;
    short* lB = Bs + wave * 512;

    f32x4 acc[4][4];
#pragma unroll
    for (int i = 0; i < 4; ++i)
#pragma unroll
        for (int j = 0; j < 4; ++j) acc[i][j] = (f32x4){0.f, 0.f, 0.f, 0.f};

    for (int k0 = 0; k0 < K; k0 += 32) {
        __syncthreads();
        gl2lds16(gA + k0,                  lA);
        gl2lds16(gA + k0 + (size_t)64 * K, lA + 2048);
        gl2lds16(gB + k0,                  lB);
        gl2lds16(gB + k0 + (size_t)64 * K, lB + 2048);
        __syncthreads();

        bf16x8 av[4], bv[4];
#pragma unroll
        for (int mt = 0; mt < 4; ++mt)
            av[mt] = *(const bf16x8*)&As[(wm + mt * 16 + l16) * 32 + quad * 8];
#pragma unroll
        for (int nt = 0; nt < 4; ++nt)
            bv[nt] = *(const bf16x8*)&Bs[(wn + nt * 16 + l16) * 32 + quad * 8];
#pragma unroll
        for (int mt = 0; mt < 4; ++mt)
#pragma unroll
            for (int nt = 0; nt < 4; ++nt)
                acc[mt][nt] = __builtin_amdgcn_mfma_f32_16x16x32_bf16(
                    av[mt], bv[nt], acc[mt][nt], 0, 0, 0);
    }

#pragma unroll
    for (int mt = 0; mt < 4; ++mt)
#pragma unroll
        for (int nt = 0; nt < 4; ++nt) {
            int col = n0 + wn + nt * 16 + l16;
#pragma unroll
            for (int r = 0; r < 4; ++r) {
                int row = m0 + wm + mt * 16 + quad * 4 + r;
                C[(size_t)row * N + col] = acc[mt][nt][r];
            }
        }
}

// ---------------------------------------------------------------------------
// Fused post-GEMM layout pass: RoPE-Q (in-place fp32), RoPE-K -> bf16,
// V -> bf16 transposed. One launch, three block ranges.
// ---------------------------------------------------------------------------
__global__ void rope_cvt(float* __restrict__ qkv,
                         const float* __restrict__ cosp,
                         const float* __restrict__ sinp,
                         short* __restrict__ kb,
                         short* __restrict__ vt)
{
    int g = blockIdx.x * 256 + threadIdx.x;
    if (g < SEQ * NH * 64) {                        // RoPE Q in-place
        int d = g & 63;
        int h = (g >> 6) & (NH - 1);
        int s = g >> 10;
        float* base = qkv + (size_t)s * QKVN + h * DH;
        float x0 = base[d], x1 = base[d + 64];
        float c0 = cosp[s * DH + d],  c1 = cosp[s * DH + d + 64];
        float s0 = sinp[s * DH + d],  s1 = sinp[s * DH + d + 64];
        base[d]      = x0 * c0 - x1 * s0;
        base[d + 64] = x1 * c1 + x0 * s1;
        return;
    }
    g -= SEQ * NH * 64;
    if (g < SEQ * NKV * 64) {                       // RoPE K -> bf16
        int d   = g & 63;
        int kvh = (g >> 6) & (NKV - 1);
        int s   = g >> 7;
        const float* base = qkv + (size_t)s * QKVN + NH * DH + kvh * DH;
        float x0 = base[d], x1 = base[d + 64];
        float c0 = cosp[s * DH + d],  c1 = cosp[s * DH + d + 64];
        float s0 = sinp[s * DH + d],  s1 = sinp[s * DH + d + 64];
        short* ob = kb + (size_t)s * (NKV * DH) + kvh * DH;
        ob[d]      = f2bf(x0 * c0 - x1 * s0);
        ob[d + 64] = f2bf(x1 * c1 + x0 * s1);
        return;
    }
    g -= SEQ * NKV * 64;                            // V -> bf16 transposed
    int s   = g & (SEQ - 1);
    int d   = (g >> 11) & (DH - 1);
    int kvh = g >> 18;
    vt[g] = f2bf(qkv[(size_t)s * QKVN + NH * DH + NKV * DH + kvh * DH + d]);
}

// ---------------------------------------------------------------------------
// MFMA flash attention (R5 structure): transposed scores, 32-key tiles,
// SL*log2e folded into Q fragment, ballot-guarded O rescale.
// ---------------------------------------------------------------------------
__global__ __launch_bounds__(256) void attn_mfma(const float* __restrict__ Qp,
                                                 const short* __restrict__ Kb,
                                                 const short* __restrict__ Vtb,
                                                 short* __restrict__ ctx)
{
    __shared__ short Ks[32][136];
    __shared__ short Vs[128][40];
    __shared__ short Ps[4][16][40];    // per-wave [q][k] operand layout

    const int bid = blockIdx.x;
    const int h   = bid & 15;
    const int qb  = 31 - (bid >> 4);   // heavy q-blocks dispatch first
    const int kvh = h >> 3;
    const int tid  = threadIdx.x;
    const int wave = tid >> 6;
    const int lane = tid & 63;
    const int quad = lane >> 4;
    const int l16  = lane & 15;

    const int qrow0 = qb * 64 + wave * 16;
    const int qg    = qrow0 + l16;       // this lane's q column

    // Q fragment, B-operand layout, pre-scaled by SCALE*LOG2E
    const float SL = SCALE * LOG2E;
    bf16x8 aq[4];
    {
        const float* qsrc = Qp + (size_t)(qrow0 + l16) * QKVN + h * DH + quad * 8;
#pragma unroll
        for (int c = 0; c < 4; ++c) {
            float4 f0 = *(const float4*)(qsrc + c * 32);
            float4 f1 = *(const float4*)(qsrc + c * 32 + 4);
            bf16x8 a;
            a[0] = f2bf(f0.x * SL); a[1] = f2bf(f0.y * SL);
            a[2] = f2bf(f0.z * SL); a[3] = f2bf(f0.w * SL);
            a[4] = f2bf(f1.x * SL); a[5] = f2bf(f1.y * SL);
            a[6] = f2bf(f1.z * SL); a[7] = f2bf(f1.w * SL);
            aq[c] = a;
        }
    }

    f32x4 of[8];
#pragma unroll
    for (int t = 0; t < 8; ++t) of[t] = (f32x4){0.f, 0.f, 0.f, 0.f};
    float m_old = -1e30f, l_sum = 0.f;

    const int nkt = (qb + 1) * 2;

    for (int kt = 0; kt < nkt; ++kt) {
        const int kbase = kt * 32;
        __syncthreads();
        {   // stage K tile: 32x128 bf16 = 512 int4 chunks, 2/thread
#pragma unroll
            for (int i = 0; i < 2; ++i) {
                int cid = tid + i * 256;
                int r = cid >> 4, c = (cid & 15) * 8;
                *(int4*)&Ks[r][c] =
                    *(const int4*)(Kb + (size_t)(kbase + r) * (NKV * DH) + kvh * DH + c);
            }
        }
        {   // stage V^T tile: 128x32 bf16 = 512 int4 chunks, 2/thread
#pragma unroll
            for (int i = 0; i < 2; ++i) {
                int cid = tid + i * 256;
                int d = cid >> 2, c = (cid & 3) * 8;
                *(int4*)&Vs[d][c] =
                    *(const int4*)(Vtb + (size_t)kvh * DH * SEQ + (size_t)d * SEQ + kbase + c);
            }
        }
        __syncthreads();

        if (kbase > qrow0 + 15) continue;   // wave-uniform: fully masked tile

        // ---- S^T: D[k=quad*4+r][q=l16] = K·(Q*SL)^T, already log2 units ----
        f32x4 s0 = (f32x4){0.f, 0.f, 0.f, 0.f};
        f32x4 s1 = (f32x4){0.f, 0.f, 0.f, 0.f};
#pragma unroll
        for (int c = 0; c < 4; ++c) {
            bf16x8 ak0 = *(const bf16x8*)&Ks[l16][c * 32 + quad * 8];
            bf16x8 ak1 = *(const bf16x8*)&Ks[16 + l16][c * 32 + quad * 8];
            s0 = __builtin_amdgcn_mfma_f32_16x16x32_bf16(ak0, aq[c], s0, 0, 0, 0);
            s1 = __builtin_amdgcn_mfma_f32_16x16x32_bf16(ak1, aq[c], s1, 0, 0, 0);
        }

        // ---- per-lane-column online softmax (log2 domain) ----
        float x[8];
#pragma unroll
        for (int r = 0; r < 4; ++r) {
            x[r]     = (kbase + quad * 4 + r      <= qg) ? s0[r] : -1e30f;
            x[4 + r] = (kbase + 16 + quad * 4 + r <= qg) ? s1[r] : -1e30f;
        }
        float mr = x[0];
#pragma unroll
        for (int i = 1; i < 8; ++i) mr = fmaxf(mr, x[i]);
        mr = fmaxf(mr, __shfl_xor(mr, 16));
        mr = fmaxf(mr, __shfl_xor(mr, 32));
        float mn    = fmaxf(m_old, mr);
        float alpha = __builtin_amdgcn_exp2f(m_old - mn);
        float p[8], ps = 0.f;
#pragma unroll
        for (int i = 0; i < 8; ++i) { p[i] = __builtin_amdgcn_exp2f(x[i] - mn); ps += p[i]; }
        ps += __shfl_xor(ps, 16);
        ps += __shfl_xor(ps, 32);
        l_sum = l_sum * alpha + ps;

        // P^T (C-layout) -> Ps[wave][q=l16][k] (operand layout), 2x b64
        bf16x4 w0 = { f2bf(p[0]), f2bf(p[1]), f2bf(p[2]), f2bf(p[3]) };
        bf16x4 w1 = { f2bf(p[4]), f2bf(p[5]), f2bf(p[6]), f2bf(p[7]) };
        *(bf16x4*)&Ps[wave][l16][quad * 4]      = w0;
        *(bf16x4*)&Ps[wave][l16][16 + quad * 4] = w1;

        // rescale O^T only if some lane's max moved (wave-uniform branch)
        if (__ballot(mn > m_old)) {
#pragma unroll
            for (int t = 0; t < 8; ++t)
#pragma unroll
                for (int r = 0; r < 4; ++r) of[t][r] *= alpha;
        }
        m_old = mn;

        // ---- O^T += V^T @ P  (wave-private Ps round-trip) ----
        bf16x8 bp = *(const bf16x8*)&Ps[wave][l16][quad * 8];
#pragma unroll
        for (int t = 0; t < 8; ++t) {
            bf16x8 av = *(const bf16x8*)&Vs[t * 16 + l16][quad * 8];
            of[t] = __builtin_amdgcn_mfma_f32_16x16x32_bf16(av, bp, of[t], 0, 0, 0);
        }
    }

    // epilogue: O^T col=q (this lane), row d = t*16+quad*4+r; 8x 8B stores
    float inv = 1.f / l_sum;
    short* dst = ctx + (size_t)qg * HID + h * DH + quad * 4;
#pragma unroll
    for (int t = 0; t < 8; ++t) {
        bf16x4 wv = { f2bf(of[t][0] * inv), f2bf(of[t][1] * inv),
                      f2bf(of[t][2] * inv), f2bf(of[t][3] * inv) };
        *(bf16x4*)(dst + t * 16) = wv;
    }
}

// ---------------------------------------------------------------------------
extern "C" void kernel_launch(void* const* d_in, const int* in_sizes, int n_in,
                              void* d_out, int out_size, void* d_ws, size_t ws_size,
                              hipStream_t stream)
{
    const float* hs   = (const float*)d_in[0];
    const float* cosp = (const float*)d_in[1];
    const float* sinp = (const float*)d_in[2];
    const float* Wq = (const float*)d_in[4];
    const float* bq = (const float*)d_in[5];
    const float* Wk = (const float*)d_in[6];
    const float* bk = (const float*)d_in[7];
    const float* Wv = (const float*)d_in[8];
    const float* bv = (const float*)d_in[9];
    const float* Wo = (const float*)d_in[10];
    float* out = (float*)d_out;

    char* w = (char*)d_ws;
    short* btq  = (short*)w;  w += (size_t)QKVN * HID * 2;          // 10 MB
    short* wot  = (short*)w;  w += (size_t)HID * HID * 2;           //  8 MB
    float* qkv  = (float*)w;  w += (size_t)SEQ * QKVN * 4;          // 20 MB
    short* kbf  = (short*)w;  w += (size_t)SEQ * (NKV * DH) * 2;    //  1 MB
    short* vtb  = (short*)w;  w += (size_t)NKV * DH * SEQ * 2;      //  1 MB
    short* ctxb = (short*)w;                                        //  8 MB

    // 1. all weight transposes (fp32 [K][N] -> bf16 [N][K])
    transp_all<<<9216, dim3(32, 8), 0, stream>>>(Wq, Wk, Wv, Wo, btq, wot);

    // 2. fused QKV projection (fp32 A converted in-kernel, bias fused)
    gemm_qkv<<<dim3(QKVN / 128, SEQ / 128), 256, 0, stream>>>(hs, btq, bq, bk, bv, qkv);

    // 3. RoPE Q/K + V transpose, one launch
    {
        int total = SEQ * NH * 64 + SEQ * NKV * 64 + NKV * DH * SEQ;
        rope_cvt<<<total / 256, 256, 0, stream>>>(qkv, cosp, sinp, kbf, vtb);
    }

    // 4. attention (bf16 ctx out)
    attn_mfma<<<dim3(32 * NH), 256, 0, stream>>>(qkv, kbf, vtb, ctxb);

    // 5. output projection
    gemm_bt<<<dim3(HID / 128, SEQ / 128), 256, 0, stream>>>(ctxb, wot, out, SEQ, HID, HID);
}